// Round 2
// baseline (1922.064 us; speedup 1.0000x reference)
//
#include <hip/hip_runtime.h>

// Match numpy's rounding exactly: no FMA contraction, same op order as reference.
#pragma clang fp contract(off)

#define B_    4
#define NT_   256
#define NZ_   192
#define NX_   192
#define NREC_ 128
#define DT_   0.001f
#define DH_   10.0f

#define N_CELL  (NZ_ * NX_)        // 36864
#define N_FIELD (B_ * N_CELL)      // 147456

// ---------------- material precompute ----------------
__global__ void mat_kernel(const float* __restrict__ vp, const float* __restrict__ vs,
                           const float* __restrict__ rho,
                           float* __restrict__ lam, float* __restrict__ dtmu,
                           float* __restrict__ lam2mu, float* __restrict__ buoy) {
    int i = blockIdx.x * blockDim.x + threadIdx.x;
    if (i >= N_CELL) return;
    float vpi = vp[i], vsi = vs[i], rhoi = rho[i];
    float vs2 = vsi * vsi;
    float mui = rhoi * vs2;
    float lami = rhoi * (vpi * vpi - 2.0f * vs2);
    lam[i] = lami;
    dtmu[i] = DT_ * mui;             // reference: DT * mu * (...) == (DT*mu) * (...)
    lam2mu[i] = lami + 2.0f * mui;
    buoy[i] = DT_ / rhoi;
}

// ---------------- velocity update ----------------
// vx += buoy * (dxf(txx) + dzb(txz))
// vz += buoy * (dxb(txz) + dzf(tzz))
__global__ void vel_kernel(float* __restrict__ vx, float* __restrict__ vz,
                           const float* __restrict__ txx, const float* __restrict__ tzz,
                           const float* __restrict__ txz, const float* __restrict__ buoy) {
    int i = blockIdx.x * blockDim.x + threadIdx.x;
    if (i >= N_FIELD) return;
    int c = i % N_CELL;
    int z = c / NX_;
    int x = c % NX_;

    float txx_c = txx[i];
    float txz_c = txz[i];

    float dxf_txx = (x < NX_ - 1) ? (txx[i + 1] - txx_c) / DH_ : 0.0f;
    float dzb_txz = (z >= 1)      ? (txz_c - txz[i - NX_]) / DH_ : 0.0f;
    float dxb_txz = (x >= 1)      ? (txz_c - txz[i - 1]) / DH_ : 0.0f;
    float dzf_tzz = (z < NZ_ - 1) ? (tzz[i + NX_] - tzz[i]) / DH_ : 0.0f;

    float bu = buoy[c];
    vx[i] = vx[i] + bu * (dxf_txx + dzb_txz);
    vz[i] = vz[i] + bu * (dxb_txz + dzf_tzz);
}

// ---------------- stress update + source + record ----------------
// Runs after vel_kernel: vx/vz here are post-update => record them (scan records
// end-of-step vx/vz, which the stress update does not modify).
__global__ void stress_kernel(const float* __restrict__ vx, const float* __restrict__ vz,
                              float* __restrict__ txx, float* __restrict__ tzz,
                              float* __restrict__ txz,
                              const float* __restrict__ lam, const float* __restrict__ dtmu,
                              const float* __restrict__ lam2mu,
                              const float* __restrict__ wav, int t,
                              const int* __restrict__ src_loc, const int* __restrict__ rec_loc,
                              float* __restrict__ out) {
    int i = blockIdx.x * blockDim.x + threadIdx.x;

    // receiver recording (B*NREC = 512 threads)
    // Output layout: (NT, NREC, 2B) — out[t, r, b] = vx, out[t, r, B+b] = vz
    if (i < B_ * NREC_) {
        int b = i / NREC_;
        int r = i % NREC_;
        int rz = rec_loc[2 * r];
        int rx = rec_loc[2 * r + 1];
        int idx = b * N_CELL + rz * NX_ + rx;
        size_t o = ((size_t)t * NREC_ + r) * (2 * B_);
        out[o + b]      = vx[idx];
        out[o + B_ + b] = vz[idx];
    }

    if (i >= N_FIELD) return;
    int b = i / N_CELL;
    int c = i % N_CELL;
    int z = c / NX_;
    int x = c % NX_;

    float vx_c = vx[i];
    float vz_c = vz[i];

    float dvxdx  = (x >= 1)      ? (vx_c - vx[i - 1]) / DH_ : 0.0f;
    float dvzdz  = (z >= 1)      ? (vz_c - vz[i - NX_]) / DH_ : 0.0f;
    float dzf_vx = (z < NZ_ - 1) ? (vx[i + NX_] - vx_c) / DH_ : 0.0f;
    float dxf_vz = (x < NX_ - 1) ? (vz[i + 1] - vz_c) / DH_ : 0.0f;

    float l   = lam[c];
    float l2m = lam2mu[c];

    float new_txx = txx[i] + DT_ * (l2m * dvxdx + l * dvzdz);
    float new_tzz = tzz[i] + DT_ * (l * dvxdx + l2m * dvzdz);
    float new_txz = txz[i] + dtmu[c] * (dzf_vx + dxf_vz);

    // source injection at (b, sz, sx)
    if (z == src_loc[2 * b] && x == src_loc[2 * b + 1]) {
        float w = wav[b * NT_ + t];
        new_txx = new_txx + w;
        new_tzz = new_tzz + w;
    }

    txx[i] = new_txx;
    tzz[i] = new_tzz;
    txz[i] = new_txz;
}

extern "C" void kernel_launch(void* const* d_in, const int* in_sizes, int n_in,
                              void* d_out, int out_size, void* d_ws, size_t ws_size,
                              hipStream_t stream) {
    const float* xw      = (const float*)d_in[0];   // (B, NT, 1)
    const float* vp      = (const float*)d_in[1];   // (NZ, NX)
    const float* vs      = (const float*)d_in[2];
    const float* rho     = (const float*)d_in[3];
    const int*   src_loc = (const int*)d_in[4];     // (B, 2)
    const int*   rec_loc = (const int*)d_in[5];     // (NREC, 2)
    float*       out     = (float*)d_out;

    float* ws    = (float*)d_ws;
    float* vx    = ws + 0 * N_FIELD;
    float* vz    = ws + 1 * N_FIELD;
    float* txx   = ws + 2 * N_FIELD;
    float* tzz   = ws + 3 * N_FIELD;
    float* txz   = ws + 4 * N_FIELD;
    float* lam    = ws + 5 * N_FIELD;
    float* dtmu   = lam + N_CELL;
    float* lam2mu = dtmu + N_CELL;
    float* buoy   = lam2mu + N_CELL;

    // zero the 5 wavefields
    hipMemsetAsync(d_ws, 0, (size_t)5 * N_FIELD * sizeof(float), stream);

    mat_kernel<<<(N_CELL + 255) / 256, 256, 0, stream>>>(vp, vs, rho, lam, dtmu, lam2mu, buoy);

    const int blocks = (N_FIELD + 255) / 256;  // 576
    for (int t = 0; t < NT_; ++t) {
        vel_kernel<<<blocks, 256, 0, stream>>>(vx, vz, txx, tzz, txz, buoy);
        stress_kernel<<<blocks, 256, 0, stream>>>(vx, vz, txx, tzz, txz,
                                                  lam, dtmu, lam2mu,
                                                  xw, t, src_loc, rec_loc, out);
    }
}